// Round 5
// baseline (7363.610 us; speedup 1.0000x reference)
//
#include <hip/hip_runtime.h>

typedef unsigned short u16;
typedef unsigned int   u32;

// ---- bf16 helpers (store with round-to-nearest-even) ----
static __device__ __forceinline__ float bf2f(u16 v){ return __uint_as_float(((u32)v)<<16); }
static __device__ __forceinline__ u16 f2bf(float f){
  u32 u = __float_as_uint(f);
  u32 r = (u + 0x7fffu + ((u>>16)&1u)) >> 16;
  return (u16)r;
}
static __device__ __forceinline__ float cvt(float v){ return v; }
static __device__ __forceinline__ float cvt(u16 v){ return bf2f(v); }
static __device__ __forceinline__ void stv(float* p, float v){ *p = v; }
static __device__ __forceinline__ void stv(u16* p, float v){ *p = f2bf(v); }

// ---------------- RMSNorm, explicit: O = X / rms(X) * scale ----------------
template<typename TO>
__global__ __launch_bounds__(64) void rms_k(const float* __restrict__ X,
                                            const float* __restrict__ scale,
                                            TO* __restrict__ O)
{
  int row = blockIdx.x, lane = threadIdx.x;
  const float* xr = X + (size_t)row*384;
  float v[6]; float ss = 0.f;
#pragma unroll
  for(int i=0;i<6;i++){ v[i]=xr[lane+64*i]; ss += v[i]*v[i]; }
#pragma unroll
  for(int off=32; off>0; off>>=1) ss += __shfl_down(ss, off, 64);
  ss = __shfl(ss, 0, 64);
  float r = rsqrtf(ss*(1.0f/384.0f)+1e-6f);
  TO* orow = O + (size_t)row*384;
#pragma unroll
  for(int i=0;i<6;i++){ int c=lane+64*i; stv(&orow[c], v[i]*r*scale[c]); }
}

// ---------------- Generic GEMM, 64x64 tile, K-step 16, fp32 accumulate ----------------
// C = relu?( alpha*(A@B) + beta*R + bias )
// C/R offset = (m>>8)*cs_hi + (m&255)*cs_lo + z*{csz,rsz} + n   (handles QKV scatter)
template<typename TA, typename TB, typename TC, typename TR>
__global__ __launch_bounds__(256) void gemm_k(
    const TA* __restrict__ A, int lda, long asz,
    const TB* __restrict__ B, int ldb, long bsz,
    TC* __restrict__ C, long csz, long cs_hi, int cs_lo,
    const TR* __restrict__ R, long rsz,
    const float* __restrict__ bias,
    int M, int N, int K, float alpha, float beta, int relu)
{
  __shared__ __align__(16) float As[16][68];
  __shared__ __align__(16) float Bs[16][68];
  const int z = blockIdx.z;
  const TA* Az = A + (long)z*asz;
  const TB* Bz = B + (long)z*bsz;
  const int m0 = blockIdx.x*64, n0 = blockIdx.y*64;
  const int tid = threadIdx.x;
  const int tm = tid>>4, tn = tid&15;
  const int la_m = tid>>4, la_k = tid&15;
  const int lb_k = tid>>6, lb_n = tid&63;
  float acc[4][4];
#pragma unroll
  for(int i=0;i<4;i++)
#pragma unroll
    for(int j=0;j<4;j++) acc[i][j]=0.f;

  for(int k0=0;k0<K;k0+=16){
#pragma unroll
    for(int i=0;i<4;i++){
      int m = m0 + la_m + 16*i;
      int kk = k0 + la_k;
      As[la_k][la_m+16*i] = (kk<K) ? cvt(Az[(size_t)m*lda + kk]) : 0.f;
    }
#pragma unroll
    for(int i=0;i<4;i++){
      int kk = k0 + lb_k + 4*i;
      int n  = n0 + lb_n;
      Bs[lb_k+4*i][lb_n] = (kk<K && n<N) ? cvt(Bz[(size_t)kk*ldb + n]) : 0.f;
    }
    __syncthreads();
#pragma unroll
    for(int kk=0;kk<16;kk++){
      float4 av = *(const float4*)&As[kk][tm*4];
      float4 bv = *(const float4*)&Bs[kk][tn*4];
      acc[0][0]+=av.x*bv.x; acc[0][1]+=av.x*bv.y; acc[0][2]+=av.x*bv.z; acc[0][3]+=av.x*bv.w;
      acc[1][0]+=av.y*bv.x; acc[1][1]+=av.y*bv.y; acc[1][2]+=av.y*bv.z; acc[1][3]+=av.y*bv.w;
      acc[2][0]+=av.z*bv.x; acc[2][1]+=av.z*bv.y; acc[2][2]+=av.z*bv.z; acc[2][3]+=av.z*bv.w;
      acc[3][0]+=av.w*bv.x; acc[3][1]+=av.w*bv.y; acc[3][2]+=av.w*bv.z; acc[3][3]+=av.w*bv.w;
    }
    __syncthreads();
  }
#pragma unroll
  for(int i=0;i<4;i++){
    int m = m0 + tm*4 + i;
    long rowoff = (long)(m>>8)*cs_hi + (long)(m&255)*cs_lo;
#pragma unroll
    for(int j=0;j<4;j++){
      int n = n0 + tn*4 + j;
      if(n<N){
        float v = alpha*acc[i][j];
        if(R)    v += beta*cvt(R[rowoff + (long)z*rsz + n]);
        if(bias) v += bias[n];
        if(relu) v  = fmaxf(v, 0.f);
        stv(C + (long)z*csz + rowoff + n, v);
      }
    }
  }
}

// ---------------- Gram: G = X^T X for 384x384 fp32, batched z ----------------
__global__ __launch_bounds__(256) void gram_k(const float* __restrict__ X, long xsz,
                                              float* __restrict__ G, long gsz)
{
  __shared__ __align__(16) float As[16][68];
  __shared__ __align__(16) float Bs[16][68];
  const int z = blockIdx.z;
  const float* Xz = X + (long)z*xsz;
  float* Gz = G + (long)z*gsz;
  const int i0 = blockIdx.x*64, j0 = blockIdx.y*64;
  const int tid = threadIdx.x;
  const int tm = tid>>4, tn = tid&15;
  const int lr = tid>>6, lc = tid&63;
  float acc[4][4];
#pragma unroll
  for(int i=0;i<4;i++)
#pragma unroll
    for(int j=0;j<4;j++) acc[i][j]=0.f;

  for(int c0=0;c0<384;c0+=16){
#pragma unroll
    for(int i=0;i<4;i++){
      int c = c0 + lr + 4*i;
      As[lr+4*i][lc] = Xz[(size_t)c*384 + i0 + lc];
      Bs[lr+4*i][lc] = Xz[(size_t)c*384 + j0 + lc];
    }
    __syncthreads();
#pragma unroll
    for(int kk=0;kk<16;kk++){
      float4 av = *(const float4*)&As[kk][tm*4];
      float4 bv = *(const float4*)&Bs[kk][tn*4];
      acc[0][0]+=av.x*bv.x; acc[0][1]+=av.x*bv.y; acc[0][2]+=av.x*bv.z; acc[0][3]+=av.x*bv.w;
      acc[1][0]+=av.y*bv.x; acc[1][1]+=av.y*bv.y; acc[1][2]+=av.y*bv.z; acc[1][3]+=av.y*bv.w;
      acc[2][0]+=av.z*bv.x; acc[2][1]+=av.z*bv.y; acc[2][2]+=av.z*bv.z; acc[2][3]+=av.z*bv.w;
      acc[3][0]+=av.w*bv.x; acc[3][1]+=av.w*bv.y; acc[3][2]+=av.w*bv.z; acc[3][3]+=av.w*bv.w;
    }
    __syncthreads();
  }
#pragma unroll
  for(int i=0;i<4;i++)
#pragma unroll
    for(int j=0;j<4;j++)
      Gz[(size_t)(i0+tm*4+i)*384 + j0+tn*4+j] = acc[i][j];
}

// ---------------- Frobenius norm (inverse) of the two fp32 Wo matrices ----------------
__global__ __launch_bounds__(256) void fnorm_k(const float* __restrict__ W0,
                                               const float* __restrict__ W1,
                                               float* __restrict__ inv)
{
  const float* W = blockIdx.x ? W1 : W0;
  int tid = threadIdx.x;
  float s=0.f;
  for(int i=tid;i<147456;i+=256){ float v=W[i]; s+=v*v; }
  __shared__ float red[256];
  red[tid]=s; __syncthreads();
  for(int off=128;off>0;off>>=1){
    if(tid<off) red[tid]+=red[tid+off];
    __syncthreads();
  }
  if(tid==0) inv[blockIdx.x] = rsqrtf(red[0]);
}

__global__ __launch_bounds__(256) void nsinit_k(const float* __restrict__ W0,
                                                const float* __restrict__ W1,
                                                const float* __restrict__ inv,
                                                float* __restrict__ X)
{
  int z = blockIdx.y;
  const float* W = z ? W1 : W0;
  int i = blockIdx.x*256 + threadIdx.x;
  X[(long)z*147456 + i] = W[i]*inv[z];
}

// ---------------- Causal attention: one block per (b,h), T=256, HS=64 ----------------
// Output written fp32 to attn_cat [B,T,384].
__global__ __launch_bounds__(256) void attn_k(const u16* __restrict__ Q,
                                              const u16* __restrict__ Kg,
                                              const u16* __restrict__ Vg,
                                              float* __restrict__ O)
{
  __shared__ __align__(16) u16 KVs[256*64];     // 32 KB  (K, then reused for V)
  __shared__ __align__(16) u16 Qs[64][66];
  __shared__ float obuf[64][65];
  __shared__ float red[4][64];
  const int bh = blockIdx.x;
  const int b = bh/6, h = bh - b*6;
  const u16* Qb = Q  + (size_t)bh*16384;
  const u16* Kb = Kg + (size_t)bh*16384;
  const u16* Vb = Vg + (size_t)bh*16384;
  const int tid = threadIdx.x;
  const int g = tid>>6, r = tid&63;             // g = wave id (s-column group), r = q row

  for(int t0=0;t0<256;t0+=64){
    __syncthreads();
    {
      const uint4* src = (const uint4*)Kb;
      uint4* dst = (uint4*)KVs;
      for(int i=tid;i<2048;i+=256) dst[i]=src[i];
      const u16* qsrc = Qb + t0*64;
      for(int i=tid;i<4096;i+=256) Qs[i>>6][i&63]=qsrc[i];
      float* ob = &obuf[0][0];
      for(int i=tid;i<64*65;i+=256) ob[i]=0.f;
    }
    __syncthreads();

    const int tg = t0 + r;
    const bool active = (g*64 <= t0+63);        // wave-uniform causal tile skip
    float sc[64];
#pragma unroll
    for(int j=0;j<64;j++) sc[j]=0.f;
    if(active){
      for(int d0=0;d0<64;d0+=8){
        float qr[8];
#pragma unroll
        for(int p=0;p<4;p++){
          u32 u = *(const u32*)&Qs[r][d0+2*p];
          qr[2*p]   = __uint_as_float(u<<16);
          qr[2*p+1] = __uint_as_float(u & 0xffff0000u);
        }
        const u16* kbase = &KVs[g*64*64 + d0];
#pragma unroll
        for(int j=0;j<64;j++){
          uint4 kv = *(const uint4*)(kbase + j*64);
          sc[j] += qr[0]*__uint_as_float(kv.x<<16)
                 + qr[1]*__uint_as_float(kv.x & 0xffff0000u)
                 + qr[2]*__uint_as_float(kv.y<<16)
                 + qr[3]*__uint_as_float(kv.y & 0xffff0000u)
                 + qr[4]*__uint_as_float(kv.z<<16)
                 + qr[5]*__uint_as_float(kv.z & 0xffff0000u)
                 + qr[6]*__uint_as_float(kv.w<<16)
                 + qr[7]*__uint_as_float(kv.w & 0xffff0000u);
        }
      }
    }
    float m = -1e30f;
#pragma unroll
    for(int j=0;j<64;j++){
      int s = g*64+j;
      sc[j] = (s<=tg) ? sc[j]*0.125f : -1e30f;
      m = fmaxf(m, sc[j]);
    }
    red[g][r]=m;
    __syncthreads();
    m = fmaxf(fmaxf(red[0][r],red[1][r]), fmaxf(red[2][r],red[3][r]));
    float l = 0.f;
#pragma unroll
    for(int j=0;j<64;j++){ sc[j]=__expf(sc[j]-m); l+=sc[j]; }
    __syncthreads();
    red[g][r]=l;
    __syncthreads();
    l = red[0][r]+red[1][r]+red[2][r]+red[3][r];
    float rl = 1.f/l;
#pragma unroll
    for(int j=0;j<64;j++) sc[j]*=rl;

    __syncthreads();          // all K reads done; reload KVs with V
    {
      const uint4* src = (const uint4*)Vb;
      uint4* dst = (uint4*)KVs;
      for(int i=tid;i<2048;i+=256) dst[i]=src[i];
    }
    __syncthreads();

    for(int half=0;half<2;half++){
      float po[32];
#pragma unroll
      for(int d=0;d<32;d++) po[d]=0.f;
      if(active){
        const u16* vbase = &KVs[g*64*64 + half*32];
#pragma unroll
        for(int j=0;j<64;j++){
          float p = sc[j];
          const uint4* vr = (const uint4*)(vbase + j*64);
          uint4 v0 = vr[0], v1 = vr[1], v2 = vr[2], v3 = vr[3];
          po[0]+=p*__uint_as_float(v0.x<<16);  po[1]+=p*__uint_as_float(v0.x&0xffff0000u);
          po[2]+=p*__uint_as_float(v0.y<<16);  po[3]+=p*__uint_as_float(v0.y&0xffff0000u);
          po[4]+=p*__uint_as_float(v0.z<<16);  po[5]+=p*__uint_as_float(v0.z&0xffff0000u);
          po[6]+=p*__uint_as_float(v0.w<<16);  po[7]+=p*__uint_as_float(v0.w&0xffff0000u);
          po[8]+=p*__uint_as_float(v1.x<<16);  po[9]+=p*__uint_as_float(v1.x&0xffff0000u);
          po[10]+=p*__uint_as_float(v1.y<<16); po[11]+=p*__uint_as_float(v1.y&0xffff0000u);
          po[12]+=p*__uint_as_float(v1.z<<16); po[13]+=p*__uint_as_float(v1.z&0xffff0000u);
          po[14]+=p*__uint_as_float(v1.w<<16); po[15]+=p*__uint_as_float(v1.w&0xffff0000u);
          po[16]+=p*__uint_as_float(v2.x<<16); po[17]+=p*__uint_as_float(v2.x&0xffff0000u);
          po[18]+=p*__uint_as_float(v2.y<<16); po[19]+=p*__uint_as_float(v2.y&0xffff0000u);
          po[20]+=p*__uint_as_float(v2.z<<16); po[21]+=p*__uint_as_float(v2.z&0xffff0000u);
          po[22]+=p*__uint_as_float(v2.w<<16); po[23]+=p*__uint_as_float(v2.w&0xffff0000u);
          po[24]+=p*__uint_as_float(v3.x<<16); po[25]+=p*__uint_as_float(v3.x&0xffff0000u);
          po[26]+=p*__uint_as_float(v3.y<<16); po[27]+=p*__uint_as_float(v3.y&0xffff0000u);
          po[28]+=p*__uint_as_float(v3.z<<16); po[29]+=p*__uint_as_float(v3.z&0xffff0000u);
          po[30]+=p*__uint_as_float(v3.w<<16); po[31]+=p*__uint_as_float(v3.w&0xffff0000u);
        }
      }
      for(int gt=0; gt<4; gt++){
        if(g==gt){
#pragma unroll
          for(int d=0;d<32;d++) obuf[r][half*32+d]+=po[d];
        }
        __syncthreads();
      }
    }
    // write attn_cat[b][t0+r][h*64 + g*16 .. +15] as fp32
    float* orow = O + ((size_t)b*256 + t0 + r)*384 + h*64 + g*16;
#pragma unroll
    for(int d=0;d<16;d++) orow[d]=obuf[r][g*16+d];
  }
}

// ---------------- host-side orchestration ----------------
extern "C" void kernel_launch(void* const* d_in, const int* in_sizes, int n_in,
                              void* d_out, int out_size, void* d_ws, size_t ws_size,
                              hipStream_t stream)
{
  // Inputs fp32, output fp32 (reference dtypes; R2's NaN proved fp32-in,
  // R1/R3/R4's bit-identical 1.0722 was the u16-packed-into-fp32-out artifact).
  const float* x      = (const float*)d_in[0];
  const float* Wq     = (const float*)d_in[1];
  const float* Wk     = (const float*)d_in[2];
  const float* Wv     = (const float*)d_in[3];
  const float* Wp     = (const float*)d_in[4];
  const float* bp     = (const float*)d_in[5];
  const float* scale1 = (const float*)d_in[6];
  const float* scale2 = (const float*)d_in[7];
  const float* W1     = (const float*)d_in[8];
  const float* b1     = (const float*)d_in[9];
  const float* W2     = (const float*)d_in[10];
  const float* b2     = (const float*)d_in[11];
  const float* Wo_in  = (const float*)d_in[12];
  const float* Wo_out = (const float*)d_in[13];

  // ---- workspace layout (~292 MiB peak; d_out doubles as fp32 scratch) ----
  char* ws = (char*)d_ws;
  float* xb0 = (float*)(ws + 0);              // 2 x 384x384 fp32 (batched z)
  float* xb1 = (float*)(ws + 1179648L);
  float* gb  = (float*)(ws + 2359296L);
  float* inv = (float*)(ws + 3538944L);
  float* h1  = (float*)(ws + 4194304L);       // fp32 [65536,384] = 100,663,296 B
  float* h2  = h1;                            // in-place residual (element-wise safe)
  u16*   q   = (u16*)(ws + 104857600L);       // bf16 slots, 50,331,648 B each
  u16*   k   = (u16*)(ws + 155189248L);
  u16*   v   = (u16*)(ws + 205520896L);
  float* h3  = (float*)(ws + 205520896L);     // fp32 over dead v (+ 50MB beyond), ends 306,184,192
  u16*   h5  = (u16*)(ws + 4194304L);         // over dead h1/h2 (40.2 MB)
  u16*   h6  = (u16*)(ws + 104857600L);       // over dead q
  float* attn= (float*)d_out;                 // fp32, 100,663,296 B = exactly out buffer
  float* h4  = (float*)d_out;                 // fp32, after attn is dead

  // --- orth via plain Newton-Schulz polar iteration: X <- 1.5X - 0.5X(X^T X) ---
  fnorm_k<<<2,256,0,stream>>>(Wo_in, Wo_out, inv);
  nsinit_k<<<dim3(576,2),256,0,stream>>>(Wo_in, Wo_out, inv, xb0);
  float* xa = xb0; float* xb = xb1;
  for(int it=0; it<40; ++it){
    gram_k<<<dim3(6,6,2),256,0,stream>>>(xa, 147456L, gb, 147456L);
    gemm_k<float,float,float,float><<<dim3(6,6,2),256,0,stream>>>(
        xa, 384, 147456L,  gb, 384, 147456L,
        xb, 147456L, 98304L, 384,
        xa, 147456L, nullptr,
        384, 384, 384, -0.5f, 1.5f, 0);
    float* t = xa; xa = xb; xb = t;
  }
  const float* Qin  = xa;            // even swap count -> xb0
  const float* Qout = xa + 147456;

  // --- main path ---
  rms_k<float><<<65536,64,0,stream>>>(x, scale1, h1);
  // QKV: per-head h1[65536,384] @ W*[h][384,64] -> bf16 [B,H,T,HS]
  gemm_k<float,float,u16,float><<<dim3(1024,1,6),256,0,stream>>>(
      h1,384,0L,  Wq,64,24576L,
      q,16384L, 98304L,64,  nullptr,0L, nullptr,
      65536,64,384, 1.f,0.f,0);
  gemm_k<float,float,u16,float><<<dim3(1024,1,6),256,0,stream>>>(
      h1,384,0L,  Wk,64,24576L,
      k,16384L, 98304L,64,  nullptr,0L, nullptr,
      65536,64,384, 1.f,0.f,0);
  gemm_k<float,float,u16,float><<<dim3(1024,1,6),256,0,stream>>>(
      h1,384,0L,  Wv,64,24576L,
      v,16384L, 98304L,64,  nullptr,0L, nullptr,
      65536,64,384, 1.f,0.f,0);
  attn_k<<<1536,256,0,stream>>>(q,k,v,attn);
  // h2 = attn@Wp + bp + h1  (in-place over h1; element-wise read->write per thread)
  gemm_k<float,float,float,float><<<dim3(1024,6,1),256,0,stream>>>(
      attn,384,0L,  Wp,384,0L,
      h2,0L, 98304L,384,  h1,0L, bp,
      65536,384,384, 1.f,1.f,0);
  // h3 = rmsnorm(h2)*scale2 -> fp32
  rms_k<float><<<65536,64,0,stream>>>(h2, scale2, h3);
  // h4 = h3 @ orth(Wo_in) -> fp32 (staged in d_out; attn dead)
  gemm_k<float,float,float,float><<<dim3(1024,6,1),256,0,stream>>>(
      h3,384,0L,  Qin,384,0L,
      h4,0L, 98304L,384,  nullptr,0L, nullptr,
      65536,384,384, 1.f,0.f,0);
  // h5 = relu(h4@W1 + b1)   N=307 -> bf16 (over dead h2)
  gemm_k<float,float,u16,float><<<dim3(1024,5,1),256,0,stream>>>(
      h4,384,0L,  W1,307,0L,
      h5,0L, 78592L,307,  nullptr,0L, b1,
      65536,307,384, 1.f,0.f,1);
  // h6 = h5@W2 + b2         K=307 -> bf16 (over dead q)
  gemm_k<u16,float,u16,float><<<dim3(1024,6,1),256,0,stream>>>(
      h5,307,0L,  W2,384,0L,
      h6,0L, 98304L,384,  nullptr,0L, b2,
      65536,384,307, 1.f,0.f,0);
  // out = h6 @ orth(Wo_out) + h6 -> fp32 d_out (h4 dead)
  gemm_k<u16,float,float,u16><<<dim3(1024,6,1),256,0,stream>>>(
      h6,384,0L,  Qout,384,0L,
      (float*)d_out,0L, 98304L,384,  h6,0L, nullptr,
      65536,384,384, 1.f,1.f,0);

  (void)in_sizes; (void)n_in; (void)ws_size; (void)out_size;
}